// Round 4
// baseline (70.330 us; speedup 1.0000x reference)
//
#include <hip/hip_runtime.h>

#define NB 16           // B images
#define NP 16000        // proposals per image
#define NG 256          // gt boxes per image
#define NM (NP + NG)    // proposals + gt = 16256 = 254*64
#define NSTRIP 254      // NM / 64
#define NS 512          // samples per image
#define NCLS 91
#define SL1_BETA (1.0f/9.0f)
#define LOSS_BLOCKS 256

__device__ __forceinline__ float rl_f(float v, int l) {
    return __int_as_float(__builtin_amdgcn_readlane(__float_as_int(v), l));
}

// ---------------------------------------------------------------------------
// Kernel 1 (match): one WAVE per 64-proposal strip. Each lane holds 4 GT boxes
// (g = 64k + lane) in registers. Per proposal (uniform scalar load):
//   4x predicate ballots (iou>=0.5  <=>  3*inter >= garea+ap) -> 256-bit qual
//   mask in SGPRs. qual==0 -> negative. qual==1 -> argmax = that bit (the max
//   qualifies, so argmax among qualifiers == global argmax). qual>=2 -> exact
//   cross-product argmax over the few qualifiers via readlane (ascending g =
//   first-index tie rule). Outputs: u64 posmask per strip + packed
//   (match<<16)|label per positive proposal.
// grid = (64, NB) blocks of 256 (4 waves; strips 254,255 idle).
// ---------------------------------------------------------------------------
__global__ __launch_bounds__(256) void match_kernel(
    const float4* __restrict__ props4,      // [NB*NP]
    const float4* __restrict__ gt4,         // [NB*NG]
    const int*    __restrict__ gt_labels,   // [NB*NG]
    unsigned long long* __restrict__ posmask, // [NB*NSTRIP]
    unsigned int* __restrict__ posinfo)       // [NB*NM]
{
    const int b    = blockIdx.y;
    const int wid  = threadIdx.x >> 6;
    const int lane = threadIdx.x & 63;
    const int s    = blockIdx.x * 4 + wid;
    if (s >= NSTRIP) return;

    float4 gbx[4]; float gar[4]; int glb[4];
    #pragma unroll
    for (int k = 0; k < 4; ++k) {
        int g = 64 * k + lane;
        gbx[k] = gt4[(size_t)b * NG + g];
        gar[k] = (gbx[k].z - gbx[k].x) * (gbx[k].w - gbx[k].y);
        glb[k] = gt_labels[b * NG + g];
    }

    const float4* src = (s < 250) ? (props4 + (size_t)b * NP + s * 64)
                                  : (gt4   + (size_t)b * NG + (s - 250) * 64);
    unsigned long long word = 0;

    for (int i = 0; i < 64; ++i) {
        const float4 pb = src[i];                       // wave-uniform
        const float ap = (pb.z - pb.x) * (pb.w - pb.y);
        unsigned long long bal[4];
        #pragma unroll
        for (int k = 0; k < 4; ++k) {
            float lx = fmaxf(gbx[k].x, pb.x);
            float ly = fmaxf(gbx[k].y, pb.y);
            float rx = fminf(gbx[k].z, pb.z);
            float ry = fminf(gbx[k].w, pb.w);
            float w  = fmaxf(rx - lx, 0.0f);
            float h  = fmaxf(ry - ly, 0.0f);
            float inter = w * h;
            float t = gar[k] + ap;
            bal[k] = __ballot(fmaf(inter, 3.0f, -t) >= 0.0f);
        }
        unsigned long long q = bal[0] | bal[1] | bal[2] | bal[3];
        if (q == 0) continue;                           // negative (wave-uniform)
        word |= 1ull << i;

        int pop = __popcll(bal[0]) + __popcll(bal[1]) + __popcll(bal[2]) + __popcll(bal[3]);
        int gstar;
        if (pop == 1) {
            gstar = bal[0] ? __builtin_ctzll(bal[0])
                  : bal[1] ? 64  + __builtin_ctzll(bal[1])
                  : bal[2] ? 128 + __builtin_ctzll(bal[2])
                  :          192 + __builtin_ctzll(bal[3]);
        } else {
            float ib = -1.0f, ub = 1.0f; gstar = 0;
            #pragma unroll
            for (int k = 0; k < 4; ++k) {
                unsigned long long m = bal[k];
                while (m) {
                    int l = __builtin_ctzll(m); m &= m - 1;
                    float g0 = rl_f(gbx[k].x, l), g1 = rl_f(gbx[k].y, l);
                    float g2 = rl_f(gbx[k].z, l), g3 = rl_f(gbx[k].w, l);
                    float ga = rl_f(gar[k], l);
                    float lx = fmaxf(g0, pb.x), ly = fmaxf(g1, pb.y);
                    float rx = fminf(g2, pb.z), ry = fminf(g3, pb.w);
                    float w  = fmaxf(rx - lx, 0.0f), h = fmaxf(ry - ly, 0.0f);
                    float inter = w * h;
                    float u = (ga + ap) - inter;
                    // ascending g + strict improve == first-max tie rule
                    if (inter * ub > ib * u) { ib = inter; ub = u; gstar = 64 * k + l; }
                }
            }
        }
        int kk = gstar >> 6, ll = gstar & 63;
        int lbl;
        if      (kk == 0) lbl = __builtin_amdgcn_readlane(glb[0], ll);
        else if (kk == 1) lbl = __builtin_amdgcn_readlane(glb[1], ll);
        else if (kk == 2) lbl = __builtin_amdgcn_readlane(glb[2], ll);
        else              lbl = __builtin_amdgcn_readlane(glb[3], ll);
        if (lane == 0)
            posinfo[(size_t)b * NM + s * 64 + i] = ((unsigned)gstar << 16) | (unsigned)lbl;
    }
    if (lane == 0) posmask[b * NSTRIP + s] = word;
}

// ---------------------------------------------------------------------------
// Kernel 2: per-image balanced sampler (deterministic first-k) + box encoding.
// grid = NB, block = 256. Thread t<254 owns posmask word t (64 contiguous
// proposals); nmask = ~pmask (no ignore band). One shfl block-scan
// (2 barriers), direct-slot writes. Encode only positives (loss never reads
// negatives' regression targets).
// ---------------------------------------------------------------------------
__global__ __launch_bounds__(256) void sample_kernel(
    const float4* __restrict__ props4,
    const float4* __restrict__ gt4,
    const float*  __restrict__ gt_thetas,
    const unsigned long long* __restrict__ posmask,
    const unsigned int* __restrict__ posinfo,
    int*   __restrict__ labels_out,   // [NB*NS]
    float* __restrict__ regt_out)     // [NB*NS*5]
{
    __shared__ int sampled[NS];
    __shared__ int wsum[4];

    const int b    = blockIdx.x;
    const int tid  = threadIdx.x;
    const int lane = tid & 63;
    const int wid  = tid >> 6;

    unsigned long long pm = 0ull, nm = 0ull;
    if (tid < NSTRIP) { pm = posmask[b * NSTRIP + tid]; nm = ~pm; }
    int cp = __popcll(pm), cn = __popcll(nm);
    int val  = (cp << 16) | cn;
    int incl = val;
    #pragma unroll
    for (int off = 1; off < 64; off <<= 1) {
        int u = __shfl_up(incl, off, 64);
        if (lane >= off) incl += u;
    }
    if (lane == 63) wsum[wid] = incl;
    __syncthreads();
    int wbase = 0;
    #pragma unroll
    for (int w = 0; w < 4; ++w) if (w < wid) wbase += wsum[w];
    int tot  = wsum[0] + wsum[1] + wsum[2] + wsum[3];
    int excl = wbase + incl - val;
    int rp = excl >> 16, rn = excl & 0xffff;
    int posT = tot >> 16, negT = tot & 0xffff;
    int np = posT < 128 ? posT : 128;          // n_pos = min(pos_total, S/4)
    int nn = NS - np; if (nn > negT) nn = negT;

    const int base = tid * 64;
    if (tid < NSTRIP) {
        #pragma unroll 4
        for (int e = 0; e < 64; ++e) {
            int idx = base + e;
            if ((pm >> e) & 1ull) {
                if (rp < np) sampled[rp + (rn < nn ? rn : nn)] = idx;
                rp++;
            } else {
                if (rn < nn) sampled[rn + (rp < np ? rp : np)] = idx;
                rn++;
            }
        }
    }
    __syncthreads();
    // Fallback fill (unreachable with this data): unselected ascending.
    if (tid == 0 && np + nn < NS) {
        int cpp = 0, cnn = 0, i = np + nn;
        for (int idx = 0; idx < NM && i < NS; ++idx) {
            unsigned long long w = posmask[b * NSTRIP + (idx >> 6)];
            bool p = (w >> (idx & 63)) & 1ull;
            bool sel;
            if (p) { sel = cpp < np; cpp++; } else { sel = cnn < nn; cnn++; }
            if (!sel) sampled[i++] = idx;
        }
    }
    __syncthreads();

    for (int i = tid; i < NS; i += 256) {
        int idx = sampled[i];
        unsigned long long w = posmask[b * NSTRIP + (idx >> 6)];
        bool pos = (w >> (idx & 63)) & 1ull;
        int lbl = 0;
        if (pos) {
            unsigned info = posinfo[(size_t)b * NM + idx];
            int m = info >> 16; lbl = info & 0xffff;
            float4 pv = (idx < NP) ? props4[(size_t)b * NP + idx]
                                   : gt4[(size_t)b * NG + (idx - NP)];
            float4 rv = gt4[(size_t)b * NG + m];
            float pw = pv.z - pv.x, ph = pv.w - pv.y;
            float px = pv.x + 0.5f * pw, py = pv.y + 0.5f * ph;
            float gw = rv.z - rv.x, gh = rv.w - rv.y;
            float gx = rv.x + 0.5f * gw, gy = rv.y + 0.5f * gh;
            float* o = regt_out + ((size_t)b * NS + i) * 5;
            o[0] = 10.0f * (gx - px) / pw;
            o[1] = 10.0f * (gy - py) / ph;
            o[2] = 5.0f * logf(gw / pw);
            o[3] = 5.0f * logf(gh / ph);
            o[4] = gt_thetas[b * NG + m];
        }
        labels_out[b * NS + i] = lbl;
    }
}

// ---------------------------------------------------------------------------
// Kernel 3: fused CE (log-softmax over 91) + smooth-L1 box loss.
// One wave per row, grid-stride; per-block float2 partial (no atomics).
// row[lab] fetched via shfl from already-loaded registers; smooth-L1 spread
// over lanes 0..4.
// ---------------------------------------------------------------------------
__global__ __launch_bounds__(256) void loss_kernel(
    const float* __restrict__ logits,     // [N, 91]
    const float* __restrict__ boxreg,     // [N, 455]
    const int*   __restrict__ labels,     // [N]
    const float* __restrict__ regt,       // [N, 5]
    float2* __restrict__ partials)        // [LOSS_BLOCKS]
{
    const int wave  = threadIdx.x >> 6;
    const int lane  = threadIdx.x & 63;
    const int gwave = blockIdx.x * 4 + wave;
    const int NWAVE = LOSS_BLOCKS * 4;
    const int N     = NB * NS;

    float cls_acc = 0.0f, box_acc = 0.0f;

    for (int r = gwave; r < N; r += NWAVE) {
        const float* row = logits + (size_t)r * NCLS;
        float a = (lane < NCLS)      ? row[lane]      : -3.0e38f;
        float c = (lane + 64 < NCLS) ? row[lane + 64] : -3.0e38f;
        float mx = fmaxf(a, c);
        #pragma unroll
        for (int o = 32; o; o >>= 1) mx = fmaxf(mx, __shfl_xor(mx, o, 64));
        float ssum = 0.0f;
        if (lane < NCLS)      ssum += expf(a - mx);
        if (lane + 64 < NCLS) ssum += expf(c - mx);
        #pragma unroll
        for (int o = 32; o; o >>= 1) ssum += __shfl_xor(ssum, o, 64);

        int lab = labels[r];                               // uniform broadcast
        float xl = (lab < 64) ? __shfl(a, lab, 64) : __shfl(c, lab - 64, 64);
        if (lane == 0) cls_acc += -(xl - mx - logf(ssum));

        if (lab > 0) {                                     // uniform branch
            float d = 0.0f;
            if (lane < 5) {
                float pv = boxreg[(size_t)r * (NCLS * 5) + lab * 5 + lane];
                float tv = regt[(size_t)r * 5 + lane];
                d = pv - tv;
            }
            float ad = fabsf(d);
            float sl = (ad < SL1_BETA) ? 0.5f * d * d / SL1_BETA : ad - 0.5f * SL1_BETA;
            sl += __shfl_xor(sl, 4, 8);
            sl += __shfl_xor(sl, 2, 8);
            sl += __shfl_xor(sl, 1, 8);
            if (lane == 0) box_acc += sl;
        }
    }

    __shared__ float cpart[4], bpart[4];
    if (lane == 0) { cpart[wave] = cls_acc; bpart[wave] = box_acc; }
    __syncthreads();
    if (threadIdx.x == 0) {
        partials[blockIdx.x] = make_float2(cpart[0] + cpart[1] + cpart[2] + cpart[3],
                                           bpart[0] + bpart[1] + bpart[2] + bpart[3]);
    }
}

// ---------------------------------------------------------------------------
// Kernel 4: reduce LOSS_BLOCKS float2 partials -> 2 outputs.
// ---------------------------------------------------------------------------
__global__ void final_kernel(const float2* __restrict__ partials,
                             float* __restrict__ out)
{
    const int tid  = threadIdx.x;
    const int lane = tid & 63;
    const int wid  = tid >> 6;
    float2 v = (tid < LOSS_BLOCKS) ? partials[tid] : make_float2(0.f, 0.f);
    float c = v.x, bx = v.y;
    #pragma unroll
    for (int o = 32; o; o >>= 1) {
        c  += __shfl_xor(c, o, 64);
        bx += __shfl_xor(bx, o, 64);
    }
    __shared__ float cc[4], bb[4];
    if (lane == 0) { cc[wid] = c; bb[wid] = bx; }
    __syncthreads();
    if (tid == 0) {
        const float invN = 1.0f / (float)(NB * NS);
        out[0] = (cc[0] + cc[1] + cc[2] + cc[3]) * invN;
        out[1] = (bb[0] + bb[1] + bb[2] + bb[3]) * invN;
    }
}

// ---------------------------------------------------------------------------
extern "C" void kernel_launch(void* const* d_in, const int* in_sizes, int n_in,
                              void* d_out, int out_size, void* d_ws, size_t ws_size,
                              hipStream_t stream)
{
    const float* class_logits   = (const float*)d_in[0];  // [NB*NS, 91]
    const float* box_regression = (const float*)d_in[1];  // [NB*NS, 455]
    const float4* props4        = (const float4*)d_in[2]; // [NB, NP]
    const float4* gt4           = (const float4*)d_in[3]; // [NB, NG]
    const float* gt_thetas      = (const float*)d_in[4];  // [NB, NG]
    const int*   gt_labels      = (const int*)d_in[5];    // [NB, NG]
    float* out = (float*)d_out;

    char* ws = (char*)d_ws;
    unsigned long long* posmask = (unsigned long long*)ws;            // NB*NSTRIP u64
    unsigned int* posinfo = (unsigned int*)(ws + ((size_t)NB * NSTRIP * 8 + 255 & ~255ull));
    float2* partials = (float2*)((char*)posinfo + ((size_t)NB * NM * 4 + 255 & ~255ull));
    int* labs   = (int*)((char*)partials + (LOSS_BLOCKS * sizeof(float2) + 255 & ~255ull));
    float* regt = (float*)(labs + (size_t)NB * NS);

    hipLaunchKernelGGL(match_kernel, dim3(64, NB), dim3(256), 0, stream,
                       props4, gt4, gt_labels, posmask, posinfo);
    hipLaunchKernelGGL(sample_kernel, dim3(NB), dim3(256), 0, stream,
                       props4, gt4, gt_thetas, posmask, posinfo, labs, regt);
    hipLaunchKernelGGL(loss_kernel, dim3(LOSS_BLOCKS), dim3(256), 0, stream,
                       class_logits, box_regression, labs, regt, partials);
    hipLaunchKernelGGL(final_kernel, dim3(1), dim3(256), 0, stream, partials, out);
}

// Round 5
// 55.556 us; speedup vs baseline: 1.2659x; 1.2659x over previous
//
#include <hip/hip_runtime.h>

#define NB 16           // B images
#define NP 16000        // proposals per image (= 250*64)
#define NG 256          // gt boxes per image
#define NM (NP + NG)    // proposals + gt = 16256 = 254*64
#define NSTRIP 254      // NM / 64
#define NS 512          // samples per image
#define NCLS 91
#define SL1_BETA (1.0f/9.0f)
#define LOSS_BLOCKS 512

// ---------------------------------------------------------------------------
// Kernel 1 (match): thread-per-proposal, GTs in LDS. Inner loop computes ONLY
// the exact qualifier predicate  iou >= 0.5  <=>  3*inter >= ap+garea
// (fmaf single-rounding preserves the sign => exact), building an 8-word
// qualifier bitmask. qcnt==0 -> negative; qcnt==1 -> argmax is that bit (the
// global max qualifies whenever any qualifier exists); qcnt>=2 (rare) ->
// exact cross-product argmax over set bits only (ascending g = first-max tie
// rule). Strips 250..253 are the appended GT rows: self-IoU = 1.0 => positive
// with match = self, no loop needed.
// Outputs: u64 positive-mask per 64-strip + packed (match<<16)|label per
// positive proposal.  grid = (64, NB) x 256.
// ---------------------------------------------------------------------------
__global__ __launch_bounds__(256) void match_kernel(
    const float4* __restrict__ props4,        // [NB*NP]
    const float4* __restrict__ gt4,           // [NB*NG]
    const int*    __restrict__ gt_labels,     // [NB*NG]
    unsigned long long* __restrict__ posmask, // [NB*NSTRIP]
    unsigned int* __restrict__ posinfo)       // [NB*NM]
{
    __shared__ float4   gbox[NG];     // 4 KB
    __shared__ float    gar[NG];      // 1 KB
    __shared__ int      glab[NG];     // 1 KB
    __shared__ unsigned qm[256][9];   // 9 KB (pad 9: stride coprime to 32 banks)

    const int b   = blockIdx.y;
    const int tid = threadIdx.x;

    {   // 256 threads load 256 gts
        const float4 v = gt4[(size_t)b * NG + tid];
        gbox[tid] = v;
        gar[tid]  = (v.z - v.x) * (v.w - v.y);
        glab[tid] = gt_labels[b * NG + tid];
    }
    __syncthreads();

    const int j = blockIdx.x * 256 + tid;
    if (j >= NM) return;                       // wave-uniform (NM % 64 == 0)

    if (j >= NP) {                             // GT self-row: iou(self)=1.0
        int g = j - NP;
        posinfo[(size_t)b * NM + j] = ((unsigned)g << 16) | (unsigned)glab[g];
        if ((tid & 63) == 0) posmask[b * NSTRIP + (j >> 6)] = ~0ull;
        return;
    }

    const float4 p  = props4[(size_t)b * NP + j];
    const float  ap = (p.z - p.x) * (p.w - p.y);

    int qcnt = 0, gfirst = 0;
    for (int w = 0; w < 8; ++w) {
        unsigned m = 0;
        #pragma unroll
        for (int t = 0; t < 32; ++t) {
            const int g = w * 32 + t;
            const float4 gb = gbox[g];
            const float  ga = gar[g];
            float lx = fmaxf(gb.x, p.x), ly = fmaxf(gb.y, p.y);
            float rx = fminf(gb.z, p.z), ry = fminf(gb.w, p.w);
            float ww = fmaxf(rx - lx, 0.0f), hh = fmaxf(ry - ly, 0.0f);
            float inter = ww * hh;
            float tt = ga + ap;
            if (fmaf(inter, 3.0f, -tt) >= 0.0f) m |= (1u << t);
        }
        qm[tid][w] = m;
        if (qcnt == 0 && m) gfirst = w * 32 + (__ffs(m) - 1);
        qcnt += __popc(m);
    }

    const bool pos = qcnt > 0;
    unsigned long long word = __ballot(pos);
    if ((tid & 63) == 0) posmask[b * NSTRIP + (j >> 6)] = word;

    if (pos) {
        int gstar = gfirst;
        if (qcnt > 1) {                        // rare (~0.5%): exact argmax
            float ib = -1.0f, ub = 1.0f; gstar = 0;
            for (int w = 0; w < 8; ++w) {
                unsigned m = qm[tid][w];
                while (m) {
                    int t = __ffs(m) - 1; m &= m - 1;
                    int g = w * 32 + t;
                    const float4 gb = gbox[g];
                    float lx = fmaxf(gb.x, p.x), ly = fmaxf(gb.y, p.y);
                    float rx = fminf(gb.z, p.z), ry = fminf(gb.w, p.w);
                    float ww = fmaxf(rx - lx, 0.0f), hh = fmaxf(ry - ly, 0.0f);
                    float inter = ww * hh;
                    float u = (gar[g] + ap) - inter;
                    // inter/u > ib/ub  <=>  inter*ub > ib*u ; ascending g +
                    // strict improve == first-max tie rule
                    if (inter * ub > ib * u) { ib = inter; ub = u; gstar = g; }
                }
            }
        }
        posinfo[(size_t)b * NM + j] = ((unsigned)gstar << 16) | (unsigned)glab[gstar];
    }
}

// ---------------------------------------------------------------------------
// Kernel 2: per-image balanced sampler (deterministic first-k) + box encoding.
// grid = NB, block = 256. Thread t<254 owns posmask word t; nmask = ~pmask.
// One shfl block-scan (2 barriers), direct-slot writes. Encode only positives.
// ---------------------------------------------------------------------------
__global__ __launch_bounds__(256) void sample_kernel(
    const float4* __restrict__ props4,
    const float4* __restrict__ gt4,
    const float*  __restrict__ gt_thetas,
    const unsigned long long* __restrict__ posmask,
    const unsigned int* __restrict__ posinfo,
    int*   __restrict__ labels_out,   // [NB*NS]
    float* __restrict__ regt_out)     // [NB*NS*5]
{
    __shared__ int sampled[NS];
    __shared__ int wsum[4];

    const int b    = blockIdx.x;
    const int tid  = threadIdx.x;
    const int lane = tid & 63;
    const int wid  = tid >> 6;

    unsigned long long pm = 0ull, nm = 0ull;
    if (tid < NSTRIP) { pm = posmask[b * NSTRIP + tid]; nm = ~pm; }
    int cp = __popcll(pm), cn = __popcll(nm);
    int val  = (cp << 16) | cn;
    int incl = val;
    #pragma unroll
    for (int off = 1; off < 64; off <<= 1) {
        int u = __shfl_up(incl, off, 64);
        if (lane >= off) incl += u;
    }
    if (lane == 63) wsum[wid] = incl;
    __syncthreads();
    int wbase = 0;
    #pragma unroll
    for (int w = 0; w < 4; ++w) if (w < wid) wbase += wsum[w];
    int tot  = wsum[0] + wsum[1] + wsum[2] + wsum[3];
    int excl = wbase + incl - val;
    int rp = excl >> 16, rn = excl & 0xffff;
    int posT = tot >> 16, negT = tot & 0xffff;
    int np = posT < 128 ? posT : 128;          // n_pos = min(pos_total, S/4)
    int nn = NS - np; if (nn > negT) nn = negT;

    const int base = tid * 64;
    if (tid < NSTRIP) {
        #pragma unroll 4
        for (int e = 0; e < 64; ++e) {
            int idx = base + e;
            if ((pm >> e) & 1ull) {
                if (rp < np) sampled[rp + (rn < nn ? rn : nn)] = idx;
                rp++;
            } else {
                if (rn < nn) sampled[rn + (rp < np ? rp : np)] = idx;
                rn++;
            }
        }
    }
    __syncthreads();
    // Fallback fill (unreachable with this data): unselected ascending.
    if (tid == 0 && np + nn < NS) {
        int cpp = 0, cnn = 0, i = np + nn;
        for (int idx = 0; idx < NM && i < NS; ++idx) {
            unsigned long long w = posmask[b * NSTRIP + (idx >> 6)];
            bool p = (w >> (idx & 63)) & 1ull;
            bool sel;
            if (p) { sel = cpp < np; cpp++; } else { sel = cnn < nn; cnn++; }
            if (!sel) sampled[i++] = idx;
        }
    }
    __syncthreads();

    for (int i = tid; i < NS; i += 256) {
        int idx = sampled[i];
        unsigned long long w = posmask[b * NSTRIP + (idx >> 6)];
        bool pos = (w >> (idx & 63)) & 1ull;
        int lbl = 0;
        if (pos) {
            unsigned info = posinfo[(size_t)b * NM + idx];
            int m = info >> 16; lbl = info & 0xffff;
            float4 pv = (idx < NP) ? props4[(size_t)b * NP + idx]
                                   : gt4[(size_t)b * NG + (idx - NP)];
            float4 rv = gt4[(size_t)b * NG + m];
            float pw = pv.z - pv.x, ph = pv.w - pv.y;
            float px = pv.x + 0.5f * pw, py = pv.y + 0.5f * ph;
            float gw = rv.z - rv.x, gh = rv.w - rv.y;
            float gx = rv.x + 0.5f * gw, gy = rv.y + 0.5f * gh;
            float* o = regt_out + ((size_t)b * NS + i) * 5;
            o[0] = 10.0f * (gx - px) / pw;
            o[1] = 10.0f * (gy - py) / ph;
            o[2] = 5.0f * logf(gw / pw);
            o[3] = 5.0f * logf(gh / ph);
            o[4] = gt_thetas[b * NG + m];
        }
        labels_out[b * NS + i] = lbl;
    }
}

// ---------------------------------------------------------------------------
// Kernel 3: fused CE (log-softmax over 91) + smooth-L1 box loss.
// One wave per row, grid-stride (4 rows/wave at 512 blocks); per-block float2
// partial (no atomics -> deterministic).
// ---------------------------------------------------------------------------
__global__ __launch_bounds__(256) void loss_kernel(
    const float* __restrict__ logits,     // [N, 91]
    const float* __restrict__ boxreg,     // [N, 455]
    const int*   __restrict__ labels,     // [N]
    const float* __restrict__ regt,       // [N, 5]
    float2* __restrict__ partials)        // [LOSS_BLOCKS]
{
    const int wave  = threadIdx.x >> 6;
    const int lane  = threadIdx.x & 63;
    const int gwave = blockIdx.x * 4 + wave;
    const int NWAVE = LOSS_BLOCKS * 4;
    const int N     = NB * NS;

    float cls_acc = 0.0f, box_acc = 0.0f;

    for (int r = gwave; r < N; r += NWAVE) {
        const float* row = logits + (size_t)r * NCLS;
        float a = (lane < NCLS)      ? row[lane]      : -3.0e38f;
        float c = (lane + 64 < NCLS) ? row[lane + 64] : -3.0e38f;
        float mx = fmaxf(a, c);
        #pragma unroll
        for (int o = 32; o; o >>= 1) mx = fmaxf(mx, __shfl_xor(mx, o, 64));
        float ssum = 0.0f;
        if (lane < NCLS)      ssum += expf(a - mx);
        if (lane + 64 < NCLS) ssum += expf(c - mx);
        #pragma unroll
        for (int o = 32; o; o >>= 1) ssum += __shfl_xor(ssum, o, 64);

        int lab = labels[r];                               // uniform broadcast
        float xl = (lab < 64) ? __shfl(a, lab, 64) : __shfl(c, lab - 64, 64);
        if (lane == 0) cls_acc += -(xl - mx - logf(ssum));

        if (lab > 0) {                                     // uniform branch
            float d = 0.0f;
            if (lane < 5) {
                float pv = boxreg[(size_t)r * (NCLS * 5) + lab * 5 + lane];
                float tv = regt[(size_t)r * 5 + lane];
                d = pv - tv;
            }
            float ad = fabsf(d);
            float sl = (ad < SL1_BETA) ? 0.5f * d * d / SL1_BETA : ad - 0.5f * SL1_BETA;
            sl += __shfl_xor(sl, 4, 8);
            sl += __shfl_xor(sl, 2, 8);
            sl += __shfl_xor(sl, 1, 8);
            if (lane == 0) box_acc += sl;
        }
    }

    __shared__ float cpart[4], bpart[4];
    if (lane == 0) { cpart[wave] = cls_acc; bpart[wave] = box_acc; }
    __syncthreads();
    if (threadIdx.x == 0) {
        partials[blockIdx.x] = make_float2(cpart[0] + cpart[1] + cpart[2] + cpart[3],
                                           bpart[0] + bpart[1] + bpart[2] + bpart[3]);
    }
}

// ---------------------------------------------------------------------------
// Kernel 4: reduce LOSS_BLOCKS float2 partials -> 2 outputs.
// ---------------------------------------------------------------------------
__global__ void final_kernel(const float2* __restrict__ partials,
                             float* __restrict__ out)
{
    const int tid  = threadIdx.x;
    const int lane = tid & 63;
    const int wid  = tid >> 6;
    float2 v0 = partials[tid];
    float2 v1 = partials[tid + 256];
    float c = v0.x + v1.x, bx = v0.y + v1.y;
    #pragma unroll
    for (int o = 32; o; o >>= 1) {
        c  += __shfl_xor(c, o, 64);
        bx += __shfl_xor(bx, o, 64);
    }
    __shared__ float cc[4], bb[4];
    if (lane == 0) { cc[wid] = c; bb[wid] = bx; }
    __syncthreads();
    if (tid == 0) {
        const float invN = 1.0f / (float)(NB * NS);
        out[0] = (cc[0] + cc[1] + cc[2] + cc[3]) * invN;
        out[1] = (bb[0] + bb[1] + bb[2] + bb[3]) * invN;
    }
}

// ---------------------------------------------------------------------------
extern "C" void kernel_launch(void* const* d_in, const int* in_sizes, int n_in,
                              void* d_out, int out_size, void* d_ws, size_t ws_size,
                              hipStream_t stream)
{
    const float* class_logits   = (const float*)d_in[0];  // [NB*NS, 91]
    const float* box_regression = (const float*)d_in[1];  // [NB*NS, 455]
    const float4* props4        = (const float4*)d_in[2]; // [NB, NP]
    const float4* gt4           = (const float4*)d_in[3]; // [NB, NG]
    const float* gt_thetas      = (const float*)d_in[4];  // [NB, NG]
    const int*   gt_labels      = (const int*)d_in[5];    // [NB, NG]
    float* out = (float*)d_out;

    char* ws = (char*)d_ws;
    unsigned long long* posmask = (unsigned long long*)ws;            // NB*NSTRIP u64
    unsigned int* posinfo = (unsigned int*)(ws + ((size_t)NB * NSTRIP * 8 + 255 & ~255ull));
    float2* partials = (float2*)((char*)posinfo + ((size_t)NB * NM * 4 + 255 & ~255ull));
    int* labs   = (int*)((char*)partials + (LOSS_BLOCKS * sizeof(float2) + 255 & ~255ull));
    float* regt = (float*)(labs + (size_t)NB * NS);

    hipLaunchKernelGGL(match_kernel, dim3(64, NB), dim3(256), 0, stream,
                       props4, gt4, gt_labels, posmask, posinfo);
    hipLaunchKernelGGL(sample_kernel, dim3(NB), dim3(256), 0, stream,
                       props4, gt4, gt_thetas, posmask, posinfo, labs, regt);
    hipLaunchKernelGGL(loss_kernel, dim3(LOSS_BLOCKS), dim3(256), 0, stream,
                       class_logits, box_regression, labs, regt, partials);
    hipLaunchKernelGGL(final_kernel, dim3(1), dim3(256), 0, stream, partials, out);
}